// Round 7
// baseline (5758.217 us; speedup 1.0000x reference)
//
#include <hip/hip_runtime.h>

// CharLSTM forward: B=16, T=256, H=1024, V=32000
// Prep kernels (init/embed/fuse/transq), then ONE mega kernel:
//   workers  (64 blocks elected on one XCD): persistent LSTM recurrence,
//            dual-path step barrier (L2-local fast path, agent fallback,
//            self-validating), Wh register-resident, C register-resident.
//   consumers (ticket queue): 1024 Gx tiles (agent-stored, gate workers via
//            per-row counters) then 8000 Ys tiles (gated by worker progress).

typedef __bf16 bf16_t;
typedef bf16_t bf16x8 __attribute__((ext_vector_type(8)));
typedef float f32x4 __attribute__((ext_vector_type(4)));
typedef unsigned short u16;
typedef unsigned int u32;
typedef unsigned long long u64;

#define B_ 16
#define T_ 256
#define H_ 1024
#define V_ 32000
#define WORKERS 64
#define GX_TILES 1024              // 32x32 tiles of [4096 x 4096]
#define P3_TILES 8000              // 32x250 tiles of [4096 x 32000]
#define MEGA_BLOCKS (WORKERS + GX_TILES + P3_TILES + 64)

// ctl word offsets (each logical slot on its own 64B line)
#define BAR_L2 0                   // [t]*16, t in [0,256]
#define BAR_G  4352
#define GXR    8704                // [row]*16, row in [0,32)
#define CHOSEN 9216
#define XTICK  9232                // + xcd*16
#define ETICK  9376
#define WORKQ  9392
#define PROG   9408
#define CTL_WORDS 9424

__device__ __forceinline__ u16 f2bf(float x) {
  union { float f; u32 u; } v; v.f = x;
  u32 r = v.u + 0x7FFFu + ((v.u >> 16) & 1u);
  return (u16)(r >> 16);
}
__device__ __forceinline__ bf16x8 ldb8(const u16* p) {
  return *reinterpret_cast<const bf16x8*>(p);
}
__device__ __forceinline__ float fsig(float x) {
  return __builtin_amdgcn_rcpf(1.0f + __expf(-x));
}
__device__ __forceinline__ float ftanh(float x) {
  float x2 = fminf(fmaxf(2.0f * x, -80.0f), 80.0f);
  float e = __expf(x2);
  return (e - 1.0f) * __builtin_amdgcn_rcpf(e + 1.0f);
}
// L1-bypassing load that reads the LOCAL XCD L2 (fast-path barrier poll)
__device__ __forceinline__ u32 poll_l2(const u32* p) {
  u32 v;
  asm volatile("global_load_dword %0, %1, off sc0\n\t"
               "s_waitcnt vmcnt(0)"
               : "=v"(v) : "v"(p) : "memory");
  return v;
}
__device__ __forceinline__ u32 ld_agent(const u32* p) {
  return __hip_atomic_load(p, __ATOMIC_RELAXED, __HIP_MEMORY_SCOPE_AGENT);
}

// ---------------- prep kernels ----------------

__global__ void k_init(u32* Hs0u32, u32* ctl, float* bfu,
                       const float* b0, const float* b1, const float* b2, const float* b3) {
  int i = blockIdx.x * 256 + threadIdx.x;   // 64*256 = 16384
  if (i < 8192)
    __hip_atomic_store(&Hs0u32[i], 0u, __ATOMIC_RELAXED, __HIP_MEMORY_SCOPE_AGENT);
  if (i < CTL_WORDS)
    __hip_atomic_store(&ctl[i], (i == CHOSEN) ? 0xFFFFFFFFu : 0u,
                       __ATOMIC_RELAXED, __HIP_MEMORY_SCOPE_AGENT);
  if (i < 4096) {
    int g = i >> 10, u = i & 1023;
    const float* bb = (g == 0) ? b0 : (g == 1) ? b1 : (g == 2) ? b2 : b3;
    bfu[i] = bb[u];
  }
}

__global__ void k_embed(const int* __restrict__ ids, const float* __restrict__ emb,
                        u16* __restrict__ out) {
  int r = blockIdx.x;               // r = t*16 + b
  int t = r >> 4, b = r & 15;
  int row = ids[b * T_ + t];
  const f32x4 v = *(const f32x4*)&emb[(size_t)row * H_ + threadIdx.x * 4];
  ushort4 o;
  o.x = f2bf(v[0]); o.y = f2bf(v[1]); o.z = f2bf(v[2]); o.w = f2bf(v[3]);
  *(ushort4*)&out[(size_t)r * H_ + threadIdx.x * 4] = o;
}

__global__ void k_fuse4(const float* __restrict__ W0, const float* __restrict__ W1,
                        const float* __restrict__ W2, const float* __restrict__ W3,
                        u16* __restrict__ WT) {
  __shared__ float ti[64][65];
  int g = blockIdx.z;
  const float* W = (g == 0) ? W0 : (g == 1) ? W1 : (g == 2) ? W2 : W3;
  int u0 = blockIdx.x * 64, k0 = blockIdx.y * 64;
  int c = threadIdx.x & 63, rq = threadIdx.x >> 6;
#pragma unroll
  for (int p = 0; p < 16; ++p) {
    int rr = p * 4 + rq;
    ti[rr][c] = W[(size_t)(k0 + rr) * H_ + u0 + c];
  }
  __syncthreads();
#pragma unroll
  for (int p = 0; p < 16; ++p) {
    int uu = p * 4 + rq;
    WT[(size_t)(g * H_ + u0 + uu) * H_ + k0 + c] = f2bf(ti[c][uu]);
  }
}

__global__ void k_transq(const float* __restrict__ Whq, u16* __restrict__ WqT) {
  __shared__ float ti[64][65];
  int n0 = blockIdx.x * 64, k0 = blockIdx.y * 64;
  int c = threadIdx.x & 63, rq = threadIdx.x >> 6;
#pragma unroll
  for (int p = 0; p < 16; ++p) {
    int rr = p * 4 + rq;
    ti[rr][c] = Whq[(size_t)(k0 + rr) * V_ + n0 + c];
  }
  __syncthreads();
#pragma unroll
  for (int p = 0; p < 16; ++p) {
    int nn = p * 4 + rq;
    WqT[(size_t)(n0 + nn) * H_ + k0 + c] = f2bf(ti[c][nn]);
  }
}

// ---------------- device GEMM tile (128x128, 4 waves, K=1024) ----------------
// MODE 0: Gx layout out[(t*4096 + n)*16 + b], AGENT-visible stores
// MODE 1: Ys layout out[b*(T_*V_) + t*V_ + n], plain stores
template <int MODE>
__device__ void gemm_tile(const u16* __restrict__ A, const u16* __restrict__ Bt,
                          const float* __restrict__ bias, float* __restrict__ out,
                          int m0, int n0, int N, u16* As, u16* Bs) {
  const int tid = threadIdx.x;
  const int l = tid & 63, w = tid >> 6;
  const int wm = (w & 1) * 64, wn = (w >> 1) * 64;
  const int koff = (l >> 4) * 8;

  f32x4 acc[4][4] = {};

  for (int k0 = 0; k0 < H_; k0 += 32) {
#pragma unroll
    for (int c = tid; c < 512; c += 256) {
      int mm = c >> 2, kk = (c & 3) * 8;
      *(uint4*)&As[mm * 40 + kk] = *(const uint4*)&A[(size_t)(m0 + mm) * H_ + k0 + kk];
      *(uint4*)&Bs[mm * 40 + kk] = *(const uint4*)&Bt[(size_t)(n0 + mm) * H_ + k0 + kk];
    }
    __syncthreads();
    bf16x8 af[4], bfr[4];
#pragma unroll
    for (int tm = 0; tm < 4; ++tm)
      af[tm] = ldb8(&As[(wm + tm * 16 + (l & 15)) * 40 + koff]);
#pragma unroll
    for (int tn = 0; tn < 4; ++tn)
      bfr[tn] = ldb8(&Bs[(wn + tn * 16 + (l & 15)) * 40 + koff]);
#pragma unroll
    for (int tm = 0; tm < 4; ++tm)
#pragma unroll
      for (int tn = 0; tn < 4; ++tn)
        acc[tm][tn] = __builtin_amdgcn_mfma_f32_16x16x32_bf16(af[tm], bfr[tn], acc[tm][tn], 0, 0, 0);
    __syncthreads();
  }

#pragma unroll
  for (int tm = 0; tm < 4; ++tm) {
    int rbase = m0 + wm + tm * 16 + (l >> 4) * 4;
    int t = rbase >> 4;
    int bb = rbase & 15;
#pragma unroll
    for (int tn = 0; tn < 4; ++tn) {
      int n = n0 + wn + tn * 16 + (l & 15);
      float bv = bias[n];
      if (MODE == 0) {
        union { float f[2]; u64 u; } p0, p1;
        p0.f[0] = acc[tm][tn][0] + bv; p0.f[1] = acc[tm][tn][1] + bv;
        p1.f[0] = acc[tm][tn][2] + bv; p1.f[1] = acc[tm][tn][3] + bv;
        u64* o = (u64*)&out[((size_t)t * N + n) * 16 + bb];
        __hip_atomic_store(&o[0], p0.u, __ATOMIC_RELAXED, __HIP_MEMORY_SCOPE_AGENT);
        __hip_atomic_store(&o[1], p1.u, __ATOMIC_RELAXED, __HIP_MEMORY_SCOPE_AGENT);
      } else {
#pragma unroll
        for (int j = 0; j < 4; ++j) {
          out[(size_t)(bb + j) * ((size_t)T_ * V_) + (size_t)t * V_ + n] = acc[tm][tn][j] + bv;
        }
      }
    }
  }
}

// ---------------- worker: persistent LSTM recurrence ----------------
__device__ void worker_path(int wid, const u16* __restrict__ WhT,
                            const float* __restrict__ Gx, u16* __restrict__ Hs,
                            u32* __restrict__ ctl, float* __restrict__ outH,
                            float* __restrict__ outC, float (*gxs)[16][16]) {
  const int tid = threadIdx.x, l = tid & 63, w = tid >> 6;   // 4 waves
  const int gw = wid * 4 + w;                    // 0..255
  const int hu0 = gw * 4;
  const int c = l & 15;
  const int n = (c >> 2) * H_ + hu0 + (c & 3);
  const int koff = (l >> 4) * 8;
  const int m = l & 15, u = l >> 4;
  const int hu = hu0 + u;

  bf16x8 bq[32];
  {
    const u16* bp = WhT + (size_t)n * H_ + koff;
#pragma unroll
    for (int kk = 0; kk < 32; ++kk) bq[kk] = ldb8(bp + kk * 32);
  }

  float Cs = 0.0f;
  u64* HsU64 = (u64*)Hs;
  u32* barL = ctl + BAR_L2;
  u32* barG = ctl + BAR_G;
  f32x4 g4 = {};

  for (int t = 0; t < T_; ++t) {
    if (tid == 0) {
      if ((t & 7) == 0) {                         // new Gx row-block: wait producers
        while (ld_agent(&ctl[GXR + (t >> 3) * 16]) < 32u)
          __builtin_amdgcn_s_sleep(2);
      }
      if (t > 0) {
        int opened = 0;
        for (int it = 0; it < 160; ++it) {        // L2 fast path (self-validating)
          if (poll_l2(&barL[t * 16]) >= (u32)WORKERS) { opened = 1; break; }
          __builtin_amdgcn_s_sleep(1);
        }
        if (!opened) {
          while (ld_agent(&barG[t * 16]) < (u32)WORKERS)
            __builtin_amdgcn_s_sleep(2);
        }
        if (wid == 0)
          __hip_atomic_store(&ctl[PROG], (u32)t, __ATOMIC_RELAXED, __HIP_MEMORY_SCOPE_AGENT);
      }
    }
    __syncthreads();

    if ((t & 7) == 0)
      g4 = *(const f32x4*)&Gx[((size_t)t * 4096 + n) * 16 + (size_t)(l >> 4) * 4];

    const u16* ap = Hs + (size_t)t * (B_ * H_) + (size_t)m * H_ + koff;
    f32x4 a0 = {}, a1 = {}, a2 = {}, a3 = {};
#pragma unroll
    for (int kk = 0; kk < 32; kk += 4) {
      a0 = __builtin_amdgcn_mfma_f32_16x16x32_bf16(ldb8(ap + (kk + 0) * 32), bq[kk + 0], a0, 0, 0, 0);
      a1 = __builtin_amdgcn_mfma_f32_16x16x32_bf16(ldb8(ap + (kk + 1) * 32), bq[kk + 1], a1, 0, 0, 0);
      a2 = __builtin_amdgcn_mfma_f32_16x16x32_bf16(ldb8(ap + (kk + 2) * 32), bq[kk + 2], a2, 0, 0, 0);
      a3 = __builtin_amdgcn_mfma_f32_16x16x32_bf16(ldb8(ap + (kk + 3) * 32), bq[kk + 3], a3, 0, 0, 0);
    }
    f32x4 acc = (a0 + a1) + (a2 + a3);

#pragma unroll
    for (int j = 0; j < 4; ++j)
      gxs[w][(l >> 4) * 4 + j][c] = acc[j] + g4[j];

    float gi = gxs[w][m][0 + u];
    float gf = gxs[w][m][4 + u];
    float go = gxs[w][m][8 + u];
    float gc = gxs[w][m][12 + u];
    float I = fsig(gi);
    float F = fsig(gf);
    float O = fsig(go);
    float Ct = ftanh(gc);
    Cs = F * Cs + I * Ct;
    float Hn = O * ftanh(Cs);

    u32 hb = (u32)f2bf(Hn);
    u32 h1 = __shfl_down(hb, 16);
    u32 h2 = __shfl_down(hb, 32);
    u32 h3 = __shfl_down(hb, 48);
    if (l < 16) {
      u64 pk = (u64)hb | ((u64)h1 << 16) | ((u64)h2 << 32) | ((u64)h3 << 48);
      __hip_atomic_store(&HsU64[(size_t)(t + 1) * 4096 + (size_t)m * 256 + gw], pk,
                         __ATOMIC_RELAXED, __HIP_MEMORY_SCOPE_AGENT);
    }
    if (t == T_ - 1) {
      outH[(size_t)m * H_ + hu] = Hn;
      outC[(size_t)m * H_ + hu] = Cs;
    } else if (((t + 1) & 7) != 0) {
      // prefetch next step's Gx slice (row-block already confirmed ready)
      g4 = *(const f32x4*)&Gx[((size_t)(t + 1) * 4096 + n) * 16 + (size_t)(l >> 4) * 4];
    }

    // arrive: H stores visible, block-wide, then L2-local + agent counters
    asm volatile("s_waitcnt vmcnt(0)" ::: "memory");
    __syncthreads();
    if (tid == 0) {
      __hip_atomic_fetch_add(&barL[(t + 1) * 16], 1u, __ATOMIC_RELAXED, __HIP_MEMORY_SCOPE_WORKGROUP);
      __hip_atomic_fetch_add(&barG[(t + 1) * 16], 1u, __ATOMIC_RELAXED, __HIP_MEMORY_SCOPE_AGENT);
    }
  }

  if (wid == 0 && tid == 0) {       // publish final progress (Hs[256] ready)
    int opened = 0;
    for (int it = 0; it < 160; ++it) {
      if (poll_l2(&barL[256 * 16]) >= (u32)WORKERS) { opened = 1; break; }
      __builtin_amdgcn_s_sleep(1);
    }
    if (!opened) {
      while (ld_agent(&barG[256 * 16]) < (u32)WORKERS)
        __builtin_amdgcn_s_sleep(2);
    }
    __hip_atomic_store(&ctl[PROG], 256u, __ATOMIC_RELAXED, __HIP_MEMORY_SCOPE_AGENT);
  }
}

// ---------------- mega kernel ----------------
__global__ __launch_bounds__(256, 2)
void mega(const u16* __restrict__ WhT, const u16* __restrict__ WxT,
          const u16* __restrict__ WqT, const u16* __restrict__ Emb,
          float* __restrict__ Gx, u16* __restrict__ Hs,
          const float* __restrict__ bfu, const float* __restrict__ bq_out,
          float* __restrict__ out, float* __restrict__ outH, float* __restrict__ outC,
          u32* __restrict__ ctl) {
  __shared__ u16 As[128 * 40];
  __shared__ u16 Bs[128 * 40];
  __shared__ float gxs[4][16][16];
  __shared__ u32 s_tmp;
  const int tid = threadIdx.x;

  // -------- election: first WORKERS blocks on the elected XCD --------
  if (tid == 0) {
    u32 xcd;
    asm volatile("s_getreg_b32 %0, hwreg(HW_REG_XCC_ID)" : "=s"(xcd));
    xcd &= 7u;
    u32 my = __hip_atomic_fetch_add(&ctl[ETICK], 1u, __ATOMIC_RELAXED, __HIP_MEMORY_SCOPE_AGENT);
    if (my == 0)
      __hip_atomic_store(&ctl[CHOSEN], xcd, __ATOMIC_RELAXED, __HIP_MEMORY_SCOPE_AGENT);
    u32 ch;
    while ((ch = ld_agent(&ctl[CHOSEN])) > 7u)
      __builtin_amdgcn_s_sleep(2);
    int widl = -1;
    if (xcd == ch) {
      u32 tk = __hip_atomic_fetch_add(&ctl[XTICK + xcd * 16], 1u, __ATOMIC_RELAXED, __HIP_MEMORY_SCOPE_AGENT);
      if (tk < (u32)WORKERS) widl = (int)tk;
    }
    s_tmp = (u32)widl;
  }
  __syncthreads();
  const int wid = (int)s_tmp;

  if (wid >= 0) {
    worker_path(wid, WhT, Gx, Hs, ctl, outH, outC, gxs);
    return;
  }

  // -------- consumer loop: Gx tiles, then Ys tiles --------
  for (;;) {
    __syncthreads();
    if (tid == 0)
      s_tmp = __hip_atomic_fetch_add(&ctl[WORKQ], 1u, __ATOMIC_RELAXED, __HIP_MEMORY_SCOPE_AGENT);
    __syncthreads();
    u32 wk = s_tmp;
    if (wk >= (u32)(GX_TILES + P3_TILES)) return;

    if (wk < (u32)GX_TILES) {
      // Gx tile: m-major (t-ascending). m0 covers t in [m0/16, m0/16+7]
      int mt = (int)(wk >> 5), nt = (int)(wk & 31);
      gemm_tile<0>(Emb, WxT, bfu, Gx, mt * 128, nt * 128, 4096, As, Bs);
      asm volatile("s_waitcnt vmcnt(0)" ::: "memory");
      __syncthreads();
      if (tid == 0)
        __hip_atomic_fetch_add(&ctl[GXR + mt * 16], 1u, __ATOMIC_RELAXED, __HIP_MEMORY_SCOPE_AGENT);
    } else {
      // Ys tile: wait for worker progress covering rows m0..m0+127
      int idx = (int)(wk - GX_TILES);
      int mt = idx / 250, nt = idx % 250;
      if (tid == 0) {
        u32 need = (u32)(mt * 8 + 8);
        while (ld_agent(&ctl[PROG]) < need)
          __builtin_amdgcn_s_sleep(16);
      }
      __syncthreads();
      gemm_tile<1>(Hs + (size_t)B_ * H_, WqT, bq_out, out, mt * 128, nt * 128, V_, As, Bs);
    }
  }
}

// ---------------- host launcher ----------------

extern "C" void kernel_launch(void* const* d_in, const int* in_sizes, int n_in,
                              void* d_out, int out_size, void* d_ws, size_t ws_size,
                              hipStream_t stream) {
  const int*   ids = (const int*)d_in[0];
  const float* emb = (const float*)d_in[1];
  const float* Wxi = (const float*)d_in[2];
  const float* Whi = (const float*)d_in[3];
  const float* bi  = (const float*)d_in[4];
  const float* Wxf = (const float*)d_in[5];
  const float* Whf = (const float*)d_in[6];
  const float* bfv = (const float*)d_in[7];
  const float* Wxo = (const float*)d_in[8];
  const float* Who = (const float*)d_in[9];
  const float* bo  = (const float*)d_in[10];
  const float* Wxc = (const float*)d_in[11];
  const float* Whc = (const float*)d_in[12];
  const float* bc  = (const float*)d_in[13];
  const float* Whq = (const float*)d_in[14];
  const float* bq  = (const float*)d_in[15];
  float* out = (float*)d_out;

  char* ws = (char*)d_ws;
  u16* WxT = (u16*)ws;      ws += (size_t)4096 * H_ * 2;          // 8.4 MB
  u16* WhT = (u16*)ws;      ws += (size_t)4096 * H_ * 2;          // 8.4 MB
  u16* WqT = (u16*)ws;      ws += (size_t)V_ * H_ * 2;            // 65.5 MB
  u16* Emb = (u16*)ws;      ws += (size_t)T_ * B_ * H_ * 2;       // 8.4 MB
  float* Gx = (float*)ws;   ws += (size_t)T_ * 4096 * B_ * 4;     // 67 MB
  u16* Hs  = (u16*)ws;      ws += (size_t)(T_ + 1) * B_ * H_ * 2; // 8.4 MB
  float* bfu = (float*)ws;  ws += (size_t)4096 * 4;
  u32* ctl = (u32*)ws;      ws += (size_t)16384 * 4;              // 64 KB control

  // prep
  k_init<<<64, 256, 0, stream>>>((u32*)Hs, ctl, bfu, bi, bfv, bo, bc);
  k_embed<<<4096, 256, 0, stream>>>(ids, emb, Emb);
  k_fuse4<<<dim3(16, 16, 4), 256, 0, stream>>>(Wxi, Wxf, Wxo, Wxc, WxT);
  k_fuse4<<<dim3(16, 16, 4), 256, 0, stream>>>(Whi, Whf, Who, Whc, WhT);
  k_transq<<<dim3(500, 16), 256, 0, stream>>>(Whq, WqT);

  // mega: Gx producers + recurrence + Ys consumers, fully overlapped
  float* outH = out + (size_t)B_ * T_ * V_;
  float* outC = outH + (size_t)B_ * H_;
  mega<<<MEGA_BLOCKS, 256, 0, stream>>>(WhT, WxT, WqT, Emb, Gx, Hs, bfu, bq,
                                        out, outH, outC, ctl);
}

// Round 9
// 2801.950 us; speedup vs baseline: 2.0551x; 2.0551x over previous
//
#include <hip/hip_runtime.h>

// CharLSTM forward: B=16, T=256, H=1024, V=32000
//   P0 prep: fuse/transpose weights to bf16, embed gather, init state + flags
//   P1 Gx = emb @ Wx_fused + b  (m97-style MFMA GEMM, out [T][4H][B])
//   P2 persistent recurrence (r6-proven): 32 blocks x 512 thr, 256 steps,
//      flag-array barrier via agent-scope (MALL) ops. UNCHANGED from round 6.
//   P3 Ys = Hs @ W_hq + b_q  (m97-style MFMA GEMM, out [B][T][V] f32 = d_out)
// GEMM upgrade: global_load_lds width-16 staging (linear LDS, m97 structure)
// replaces reg-staged LDS. Epilogues/layouts identical to round 6.

typedef __bf16 bf16_t;
typedef bf16_t bf16x8 __attribute__((ext_vector_type(8)));
typedef float f32x4 __attribute__((ext_vector_type(4)));
typedef unsigned short u16;
typedef unsigned int u32;
typedef unsigned long long u64;

#define B_ 16
#define T_ 256
#define H_ 1024
#define V_ 32000
#define NBLK_R 32
#define FLAG_STRIDE 16     // u32s per 64B line

__device__ __forceinline__ u16 f2bf(float x) {
  union { float f; u32 u; } v; v.f = x;
  u32 r = v.u + 0x7FFFu + ((v.u >> 16) & 1u);
  return (u16)(r >> 16);
}
__device__ __forceinline__ bf16x8 ldb8(const u16* p) {
  return *reinterpret_cast<const bf16x8*>(p);
}
__device__ __forceinline__ float fsig(float x) {
  return __builtin_amdgcn_rcpf(1.0f + __expf(-x));
}
__device__ __forceinline__ float ftanh(float x) {
  float x2 = fminf(fmaxf(2.0f * x, -80.0f), 80.0f);
  float e = __expf(x2);
  return (e - 1.0f) * __builtin_amdgcn_rcpf(e + 1.0f);
}
// async global->LDS, 16B per lane; lds dest = wave-uniform base + lane*16
__device__ __forceinline__ void gll16(const void* g, void* l) {
  __builtin_amdgcn_global_load_lds(
      (const __attribute__((address_space(1))) void*)g,
      (__attribute__((address_space(3))) void*)l, 16, 0, 0);
}

// ---------------- prep kernels ----------------

__global__ void k_init(u32* Hs0u32, u32* done, float* bfu,
                       const float* b0, const float* b1, const float* b2, const float* b3) {
  int i = blockIdx.x * 256 + threadIdx.x;   // 16384
  if (i < 8192)
    __hip_atomic_store(&Hs0u32[i], 0u, __ATOMIC_RELAXED, __HIP_MEMORY_SCOPE_AGENT);
  if (i < NBLK_R * FLAG_STRIDE)
    __hip_atomic_store(&done[i], 0u, __ATOMIC_RELAXED, __HIP_MEMORY_SCOPE_AGENT);
  if (i < 4096) {
    int g = i >> 10, u = i & 1023;
    const float* bb = (g == 0) ? b0 : (g == 1) ? b1 : (g == 2) ? b2 : b3;
    bfu[i] = bb[u];
  }
}

__global__ void k_embed(const int* __restrict__ ids, const float* __restrict__ emb,
                        u16* __restrict__ out) {
  int r = blockIdx.x;               // r = t*16 + b
  int t = r >> 4, b = r & 15;
  int row = ids[b * T_ + t];
  const f32x4 v = *(const f32x4*)&emb[(size_t)row * H_ + threadIdx.x * 4];
  ushort4 o;
  o.x = f2bf(v[0]); o.y = f2bf(v[1]); o.z = f2bf(v[2]); o.w = f2bf(v[3]);
  *(ushort4*)&out[(size_t)r * H_ + threadIdx.x * 4] = o;
}

// fused: z in [0,8): z<4 -> WxT gate z; else WhT gate z-4. grid (16,16,8) x 256
__global__ void k_fuse8(const float* __restrict__ Wxi, const float* __restrict__ Wxf,
                        const float* __restrict__ Wxo, const float* __restrict__ Wxc,
                        const float* __restrict__ Whi, const float* __restrict__ Whf,
                        const float* __restrict__ Who, const float* __restrict__ Whc,
                        u16* __restrict__ WxT, u16* __restrict__ WhT) {
  __shared__ float ti[64][65];
  int z = blockIdx.z, g = z & 3;
  const float* W;
  if (z < 4) W = (g == 0) ? Wxi : (g == 1) ? Wxf : (g == 2) ? Wxo : Wxc;
  else       W = (g == 0) ? Whi : (g == 1) ? Whf : (g == 2) ? Who : Whc;
  u16* WT = (z < 4) ? WxT : WhT;
  int u0 = blockIdx.x * 64, k0 = blockIdx.y * 64;
  int c = threadIdx.x & 63, rq = threadIdx.x >> 6;
#pragma unroll
  for (int p = 0; p < 16; ++p) {
    int rr = p * 4 + rq;
    ti[rr][c] = W[(size_t)(k0 + rr) * H_ + u0 + c];
  }
  __syncthreads();
#pragma unroll
  for (int p = 0; p < 16; ++p) {
    int uu = p * 4 + rq;
    WT[(size_t)(g * H_ + u0 + uu) * H_ + k0 + c] = f2bf(ti[c][uu]);
  }
}

__global__ void k_transq(const float* __restrict__ Whq, u16* __restrict__ WqT) {
  __shared__ float ti[64][65];
  int n0 = blockIdx.x * 64, k0 = blockIdx.y * 64;
  int c = threadIdx.x & 63, rq = threadIdx.x >> 6;
#pragma unroll
  for (int p = 0; p < 16; ++p) {
    int rr = p * 4 + rq;
    ti[rr][c] = Whq[(size_t)(k0 + rr) * V_ + n0 + c];
  }
  __syncthreads();
#pragma unroll
  for (int p = 0; p < 16; ++p) {
    int nn = p * 4 + rq;
    WqT[(size_t)(n0 + nn) * H_ + k0 + c] = f2bf(ti[c][nn]);
  }
}

// ---------------- MFMA GEMM, m97 structure ----------------
// 128x128 tile, 4 waves, BK=32, linear LDS [128][32], global_load_lds staging.
// MODE 0: out[(t*N + n)*16 + b], grid (nx=N/128, ny=M/128)
// MODE 1: out[b*(T_*V_) + t*V_ + n], grid (nx=M/128, ny=N/128)  [WqT panel reuse]
template <int MODE>
__global__ __launch_bounds__(256)
void gemm_lds(const u16* __restrict__ A, const u16* __restrict__ Bt,
              const float* __restrict__ bias, float* __restrict__ out,
              int M, int N, int K) {
  __shared__ u16 As[128 * 32];   // 8 KB, linear
  __shared__ u16 Bs[128 * 32];   // 8 KB, linear
  const int tid = threadIdx.x;
  const int l = tid & 63, w = tid >> 6;
  const int m0 = (MODE == 1 ? blockIdx.x : blockIdx.y) * 128;
  const int n0 = (MODE == 1 ? blockIdx.y : blockIdx.x) * 128;
  const int wm = (w & 1) * 64, wn = (w >> 1) * 64;
  const int koff = (l >> 4) * 8;

  // staging geometry: wave w, pass p covers rows p*64 + w*16 + (l>>2),
  // 16B at element col (l&3)*8; LDS dest = base + lane*16B (linear match).
  const int srow = w * 16 + (l >> 2);
  const int scol = (l & 3) * 8;
  const u16* a0p = A + (size_t)(m0 + srow) * K + scol;
  const u16* a1p = A + (size_t)(m0 + 64 + srow) * K + scol;
  const u16* b0p = Bt + (size_t)(n0 + srow) * K + scol;
  const u16* b1p = Bt + (size_t)(n0 + 64 + srow) * K + scol;
  u16* asb0 = As + w * 512;          // w*16 rows * 32 elems
  u16* asb1 = As + 2048 + w * 512;   // rows 64+
  u16* bsb0 = Bs + w * 512;
  u16* bsb1 = Bs + 2048 + w * 512;

  f32x4 acc[4][4] = {};

  for (int k0 = 0; k0 < K; k0 += 32) {
    gll16(a0p + k0, asb0);
    gll16(a1p + k0, asb1);
    gll16(b0p + k0, bsb0);
    gll16(b1p + k0, bsb1);
    asm volatile("s_waitcnt vmcnt(0)" ::: "memory");
    __syncthreads();

    bf16x8 af[4], bfr[4];
#pragma unroll
    for (int tm = 0; tm < 4; ++tm)
      af[tm] = ldb8(&As[(wm + tm * 16 + (l & 15)) * 32 + koff]);
#pragma unroll
    for (int tn = 0; tn < 4; ++tn)
      bfr[tn] = ldb8(&Bs[(wn + tn * 16 + (l & 15)) * 32 + koff]);
#pragma unroll
    for (int tm = 0; tm < 4; ++tm)
#pragma unroll
      for (int tn = 0; tn < 4; ++tn)
        acc[tm][tn] = __builtin_amdgcn_mfma_f32_16x16x32_bf16(af[tm], bfr[tn], acc[tm][tn], 0, 0, 0);
    __syncthreads();
  }

#pragma unroll
  for (int tm = 0; tm < 4; ++tm) {
    int rbase = m0 + wm + tm * 16 + (l >> 4) * 4;
    int t = rbase >> 4;
    int bb = rbase & 15;
#pragma unroll
    for (int tn = 0; tn < 4; ++tn) {
      int n = n0 + wn + tn * 16 + (l & 15);
      float bv = bias[n];
      if (MODE == 0) {
        f32x4 v = acc[tm][tn];
        v[0] += bv; v[1] += bv; v[2] += bv; v[3] += bv;
        *(f32x4*)&out[((size_t)t * N + n) * 16 + bb] = v;
      } else {
#pragma unroll
        for (int j = 0; j < 4; ++j) {
          out[(size_t)(bb + j) * ((size_t)T_ * V_) + (size_t)t * V_ + n] = acc[tm][tn][j] + bv;
        }
      }
    }
  }
}

// ---------------- persistent LSTM recurrence (round-6 proven, UNCHANGED) ----------------
__global__ __launch_bounds__(512, 1)
void lstm_persist(const u16* __restrict__ WhT, const float* __restrict__ Gx,
                  u16* __restrict__ Hs, u32* __restrict__ done,
                  float* __restrict__ outH, float* __restrict__ outC) {
  __shared__ float gx[8][16][16];
  const int tid = threadIdx.x, l = tid & 63, w = tid >> 6;
  const int gw = blockIdx.x * 8 + w;            // 0..255
  const int hu0 = gw * 4;
  const int c = l & 15;
  const int n = (c >> 2) * H_ + hu0 + (c & 3);
  const int koff = (l >> 4) * 8;
  const int m = l & 15, u = l >> 4;
  const int hu = hu0 + u;

  bf16x8 bq[32];
  {
    const u16* bp = WhT + (size_t)n * H_ + koff;
#pragma unroll
    for (int kk = 0; kk < 32; ++kk) bq[kk] = ldb8(bp + kk * 32);
  }

  float Cs = 0.0f;
  u64* HsU64 = (u64*)Hs;
  const u32* myflag = &done[(l & 31) * FLAG_STRIDE];

  for (int t = 0; t < T_; ++t) {
    const f32x4 g4 = *(const f32x4*)&Gx[((size_t)t * 4096 + n) * 16 + (size_t)(l >> 4) * 4];

    if (t > 0) {
      if (w == 0) {
        while (true) {
          u32 v = __hip_atomic_load(myflag, __ATOMIC_RELAXED, __HIP_MEMORY_SCOPE_AGENT);
          if (__all((int)(v >= (u32)t))) break;
          __builtin_amdgcn_s_sleep(1);
        }
      }
      __syncthreads();
    }

    const u16* ap = Hs + (size_t)t * (B_ * H_) + (size_t)m * H_ + koff;
    f32x4 a0 = {}, a1 = {}, a2 = {}, a3 = {};
#pragma unroll
    for (int kk = 0; kk < 32; kk += 4) {
      a0 = __builtin_amdgcn_mfma_f32_16x16x32_bf16(ldb8(ap + (kk + 0) * 32), bq[kk + 0], a0, 0, 0, 0);
      a1 = __builtin_amdgcn_mfma_f32_16x16x32_bf16(ldb8(ap + (kk + 1) * 32), bq[kk + 1], a1, 0, 0, 0);
      a2 = __builtin_amdgcn_mfma_f32_16x16x32_bf16(ldb8(ap + (kk + 2) * 32), bq[kk + 2], a2, 0, 0, 0);
      a3 = __builtin_amdgcn_mfma_f32_16x16x32_bf16(ldb8(ap + (kk + 3) * 32), bq[kk + 3], a3, 0, 0, 0);
    }
    f32x4 acc = (a0 + a1) + (a2 + a3);

#pragma unroll
    for (int j = 0; j < 4; ++j)
      gx[w][(l >> 4) * 4 + j][c] = acc[j] + g4[j];

    float gi = gx[w][m][0 + u];
    float gf = gx[w][m][4 + u];
    float go = gx[w][m][8 + u];
    float gc = gx[w][m][12 + u];
    float I = fsig(gi);
    float F = fsig(gf);
    float O = fsig(go);
    float Ct = ftanh(gc);
    Cs = F * Cs + I * Ct;
    float Hn = O * ftanh(Cs);

    u32 hb = (u32)f2bf(Hn);
    u32 h1 = __shfl_down(hb, 16);
    u32 h2 = __shfl_down(hb, 32);
    u32 h3 = __shfl_down(hb, 48);
    if (l < 16) {
      u64 pk = (u64)hb | ((u64)h1 << 16) | ((u64)h2 << 32) | ((u64)h3 << 48);
      __hip_atomic_store(&HsU64[(size_t)(t + 1) * 4096 + (size_t)m * 256 + gw], pk,
                         __ATOMIC_RELAXED, __HIP_MEMORY_SCOPE_AGENT);
    }

    if (t == T_ - 1) {
      outH[(size_t)m * H_ + hu] = Hn;
      outC[(size_t)m * H_ + hu] = Cs;
    } else {
      asm volatile("s_waitcnt vmcnt(0)" ::: "memory");
      __syncthreads();
      if (tid == 0)
        __hip_atomic_store(&done[blockIdx.x * FLAG_STRIDE], (u32)(t + 1),
                           __ATOMIC_RELAXED, __HIP_MEMORY_SCOPE_AGENT);
    }
  }
}

// ---------------- host launcher ----------------

extern "C" void kernel_launch(void* const* d_in, const int* in_sizes, int n_in,
                              void* d_out, int out_size, void* d_ws, size_t ws_size,
                              hipStream_t stream) {
  const int*   ids = (const int*)d_in[0];
  const float* emb = (const float*)d_in[1];
  const float* Wxi = (const float*)d_in[2];
  const float* Whi = (const float*)d_in[3];
  const float* bi  = (const float*)d_in[4];
  const float* Wxf = (const float*)d_in[5];
  const float* Whf = (const float*)d_in[6];
  const float* bfv = (const float*)d_in[7];
  const float* Wxo = (const float*)d_in[8];
  const float* Who = (const float*)d_in[9];
  const float* bo  = (const float*)d_in[10];
  const float* Wxc = (const float*)d_in[11];
  const float* Whc = (const float*)d_in[12];
  const float* bc  = (const float*)d_in[13];
  const float* Whq = (const float*)d_in[14];
  const float* bq  = (const float*)d_in[15];
  float* out = (float*)d_out;

  char* ws = (char*)d_ws;
  u16* WxT = (u16*)ws;      ws += (size_t)4096 * H_ * 2;
  u16* WhT = (u16*)ws;      ws += (size_t)4096 * H_ * 2;
  u16* WqT = (u16*)ws;      ws += (size_t)V_ * H_ * 2;
  u16* Emb = (u16*)ws;      ws += (size_t)T_ * B_ * H_ * 2;
  float* Gx = (float*)ws;   ws += (size_t)T_ * 4096 * B_ * 4;
  u16* Hs  = (u16*)ws;      ws += (size_t)(T_ + 1) * B_ * H_ * 2;
  float* bfu = (float*)ws;  ws += (size_t)4096 * 4;
  u32* done = (u32*)ws;     ws += (size_t)NBLK_R * FLAG_STRIDE * 4;

  // P0: prep
  k_init<<<64, 256, 0, stream>>>((u32*)Hs, done, bfu, bi, bfv, bo, bc);
  k_embed<<<4096, 256, 0, stream>>>(ids, emb, Emb);
  k_fuse8<<<dim3(16, 16, 8), 256, 0, stream>>>(Wxi, Wxf, Wxo, Wxc, Whi, Whf, Who, Whc, WxT, WhT);
  k_transq<<<dim3(500, 16), 256, 0, stream>>>(Whq, WqT);

  // P1: Gx = emb @ Wx + b   (M=4096, N=4096, K=1024)
  gemm_lds<0><<<dim3(32, 32), 256, 0, stream>>>(Emb, WxT, bfu, Gx, 4096, 4096, H_);

  // P2: persistent recurrence (round-6 protocol)
  float* outH = out + (size_t)B_ * T_ * V_;
  float* outC = outH + (size_t)B_ * H_;
  lstm_persist<<<NBLK_R, 512, 0, stream>>>(WhT, Gx, Hs, done, outH, outC);

  // P3: Ys = Hs[1..T] @ W_hq + b_q   (M=4096, N=32000, K=1024)
  gemm_lds<1><<<dim3(32, 250), 256, 0, stream>>>(Hs + (size_t)B_ * H_, WqT, bq, out, 4096, V_, H_);
}

// Round 10
// 1830.447 us; speedup vs baseline: 3.1458x; 1.5307x over previous
//
#include <hip/hip_runtime.h>

// CharLSTM forward: B=16, T=256, H=1024, V=32000
//   P0 prep: fuse/transpose weights to bf16, embed gather, init state/ctl
//   P1 Gx = emb @ Wx_fused + b  (m97-style MFMA GEMM, out [T][4H][B])
//   P2+P3 fused kernel (256 blocks, 1/CU via 132KB LDS):
//     blocks 0-31  : persistent recurrence, r6-proven flag protocol; H exchange
//                    in FULL-LINE layout Hs[t][gw][m] (1 coalesced 128B agent
//                    store/wave/step); worker 0 publishes PROG.
//     blocks 32-255: Ys consumers; 64-col WqT strips in LDS; per mt wait
//                    PROG >= mt*8+8 then GEMM A(direct global) x B(LDS).

typedef __bf16 bf16_t;
typedef bf16_t bf16x8 __attribute__((ext_vector_type(8)));
typedef bf16_t bf16x4 __attribute__((ext_vector_type(4)));
typedef float f32x4 __attribute__((ext_vector_type(4)));
typedef unsigned short u16;
typedef unsigned int u32;
typedef unsigned long long u64;

#define B_ 16
#define T_ 256
#define H_ 1024
#define V_ 32000
#define NWORK 32
#define NCONS 224
#define NSTRIP 500          // 64-col strips of V
#define FLAG_STRIDE 16
#define PROG_IDX 512
#define CTL_WORDS 544
#define BSROW 1032          // padded LDS row (u16 elems) = 2064 B

__device__ __forceinline__ u16 f2bf(float x) {
  union { float f; u32 u; } v; v.f = x;
  u32 r = v.u + 0x7FFFu + ((v.u >> 16) & 1u);
  return (u16)(r >> 16);
}
__device__ __forceinline__ bf16x8 ldb8(const u16* p) {
  return *reinterpret_cast<const bf16x8*>(p);
}
// A-fragment from line layout: 8 units = two bf16x4 at +0 and +64 elems
__device__ __forceinline__ bf16x8 mk2(const u16* p) {
  bf16x4 lo = *reinterpret_cast<const bf16x4*>(p);
  bf16x4 hi = *reinterpret_cast<const bf16x4*>(p + 64);
  return __builtin_shufflevector(lo, hi, 0, 1, 2, 3, 4, 5, 6, 7);
}
__device__ __forceinline__ float fsig(float x) {
  return __builtin_amdgcn_rcpf(1.0f + __expf(-x));
}
__device__ __forceinline__ float ftanh(float x) {
  float x2 = fminf(fmaxf(2.0f * x, -80.0f), 80.0f);
  float e = __expf(x2);
  return (e - 1.0f) * __builtin_amdgcn_rcpf(e + 1.0f);
}
__device__ __forceinline__ void gll16(const void* g, void* l) {
  __builtin_amdgcn_global_load_lds(
      (const __attribute__((address_space(1))) void*)g,
      (__attribute__((address_space(3))) void*)l, 16, 0, 0);
}
__device__ __forceinline__ u32 ld_agent(const u32* p) {
  return __hip_atomic_load(p, __ATOMIC_RELAXED, __HIP_MEMORY_SCOPE_AGENT);
}
__device__ __forceinline__ void st_agent(u32* p, u32 v) {
  __hip_atomic_store(p, v, __ATOMIC_RELAXED, __HIP_MEMORY_SCOPE_AGENT);
}

// ---------------- prep kernels ----------------

__global__ void k_init(u32* Hs0u32, u32* ctl, float* bfu,
                       const float* b0, const float* b1, const float* b2, const float* b3) {
  int i = blockIdx.x * 256 + threadIdx.x;   // 16384
  if (i < 8192)
    __hip_atomic_store(&Hs0u32[i], 0u, __ATOMIC_RELAXED, __HIP_MEMORY_SCOPE_AGENT);
  if (i < CTL_WORDS)
    st_agent(&ctl[i], 0u);
  if (i < 4096) {
    int g = i >> 10, u = i & 1023;
    const float* bb = (g == 0) ? b0 : (g == 1) ? b1 : (g == 2) ? b2 : b3;
    bfu[i] = bb[u];
  }
}

__global__ void k_embed(const int* __restrict__ ids, const float* __restrict__ emb,
                        u16* __restrict__ out) {
  int r = blockIdx.x;               // r = t*16 + b
  int t = r >> 4, b = r & 15;
  int row = ids[b * T_ + t];
  const f32x4 v = *(const f32x4*)&emb[(size_t)row * H_ + threadIdx.x * 4];
  ushort4 o;
  o.x = f2bf(v[0]); o.y = f2bf(v[1]); o.z = f2bf(v[2]); o.w = f2bf(v[3]);
  *(ushort4*)&out[(size_t)r * H_ + threadIdx.x * 4] = o;
}

__global__ void k_fuse8(const float* __restrict__ Wxi, const float* __restrict__ Wxf,
                        const float* __restrict__ Wxo, const float* __restrict__ Wxc,
                        const float* __restrict__ Whi, const float* __restrict__ Whf,
                        const float* __restrict__ Who, const float* __restrict__ Whc,
                        u16* __restrict__ WxT, u16* __restrict__ WhT) {
  __shared__ float ti[64][65];
  int z = blockIdx.z, g = z & 3;
  const float* W;
  if (z < 4) W = (g == 0) ? Wxi : (g == 1) ? Wxf : (g == 2) ? Wxo : Wxc;
  else       W = (g == 0) ? Whi : (g == 1) ? Whf : (g == 2) ? Who : Whc;
  u16* WT = (z < 4) ? WxT : WhT;
  int u0 = blockIdx.x * 64, k0 = blockIdx.y * 64;
  int c = threadIdx.x & 63, rq = threadIdx.x >> 6;
#pragma unroll
  for (int p = 0; p < 16; ++p) {
    int rr = p * 4 + rq;
    ti[rr][c] = W[(size_t)(k0 + rr) * H_ + u0 + c];
  }
  __syncthreads();
#pragma unroll
  for (int p = 0; p < 16; ++p) {
    int uu = p * 4 + rq;
    WT[(size_t)(g * H_ + u0 + uu) * H_ + k0 + c] = f2bf(ti[c][uu]);
  }
}

__global__ void k_transq(const float* __restrict__ Whq, u16* __restrict__ WqT) {
  __shared__ float ti[64][65];
  int n0 = blockIdx.x * 64, k0 = blockIdx.y * 64;
  int c = threadIdx.x & 63, rq = threadIdx.x >> 6;
#pragma unroll
  for (int p = 0; p < 16; ++p) {
    int rr = p * 4 + rq;
    ti[rr][c] = Whq[(size_t)(k0 + rr) * V_ + n0 + c];
  }
  __syncthreads();
#pragma unroll
  for (int p = 0; p < 16; ++p) {
    int nn = p * 4 + rq;
    WqT[(size_t)(n0 + nn) * H_ + k0 + c] = f2bf(ti[c][nn]);
  }
}

// ---------------- P1 GEMM (m97 structure, MODE0 only) ----------------
__global__ __launch_bounds__(256)
void gemm_gx(const u16* __restrict__ A, const u16* __restrict__ Bt,
             const float* __restrict__ bias, float* __restrict__ out,
             int N, int K) {
  __shared__ u16 As[128 * 32];
  __shared__ u16 Bs[128 * 32];
  const int tid = threadIdx.x;
  const int l = tid & 63, w = tid >> 6;
  const int m0 = blockIdx.y * 128, n0 = blockIdx.x * 128;
  const int wm = (w & 1) * 64, wn = (w >> 1) * 64;
  const int koff = (l >> 4) * 8;

  const int srow = w * 16 + (l >> 2);
  const int scol = (l & 3) * 8;
  const u16* a0p = A + (size_t)(m0 + srow) * K + scol;
  const u16* a1p = A + (size_t)(m0 + 64 + srow) * K + scol;
  const u16* b0p = Bt + (size_t)(n0 + srow) * K + scol;
  const u16* b1p = Bt + (size_t)(n0 + 64 + srow) * K + scol;
  u16* asb0 = As + w * 512;
  u16* asb1 = As + 2048 + w * 512;
  u16* bsb0 = Bs + w * 512;
  u16* bsb1 = Bs + 2048 + w * 512;

  f32x4 acc[4][4] = {};

  for (int k0 = 0; k0 < K; k0 += 32) {
    gll16(a0p + k0, asb0);
    gll16(a1p + k0, asb1);
    gll16(b0p + k0, bsb0);
    gll16(b1p + k0, bsb1);
    asm volatile("s_waitcnt vmcnt(0)" ::: "memory");
    __syncthreads();

    bf16x8 af[4], bfr[4];
#pragma unroll
    for (int tm = 0; tm < 4; ++tm)
      af[tm] = ldb8(&As[(wm + tm * 16 + (l & 15)) * 32 + koff]);
#pragma unroll
    for (int tn = 0; tn < 4; ++tn)
      bfr[tn] = ldb8(&Bs[(wn + tn * 16 + (l & 15)) * 32 + koff]);
#pragma unroll
    for (int tm = 0; tm < 4; ++tm)
#pragma unroll
      for (int tn = 0; tn < 4; ++tn)
        acc[tm][tn] = __builtin_amdgcn_mfma_f32_16x16x32_bf16(af[tm], bfr[tn], acc[tm][tn], 0, 0, 0);
    __syncthreads();
  }

#pragma unroll
  for (int tm = 0; tm < 4; ++tm) {
    int rbase = m0 + wm + tm * 16 + (l >> 4) * 4;
    int t = rbase >> 4;
    int bb = rbase & 15;
#pragma unroll
    for (int tn = 0; tn < 4; ++tn) {
      int n = n0 + wn + tn * 16 + (l & 15);
      float bv = bias[n];
      f32x4 v = acc[tm][tn];
      v[0] += bv; v[1] += bv; v[2] += bv; v[3] += bv;
      *(f32x4*)&out[((size_t)t * N + n) * 16 + bb] = v;
    }
  }
}

// ---------------- fused: recurrence workers + Ys consumers ----------------
__global__ __launch_bounds__(512)
void fused(const u16* __restrict__ WhT, const u16* __restrict__ WqT,
           const float* __restrict__ Gx, u16* __restrict__ Hs,
           u32* __restrict__ ctl, const float* __restrict__ bqv,
           float* __restrict__ out, float* __restrict__ outH, float* __restrict__ outC) {
  __shared__ __align__(16) char ldsbuf[132096];
  const int bid = blockIdx.x;
  const int tid = threadIdx.x, l = tid & 63, w = tid >> 6;

  if (bid < NWORK) {
    // =============== WORKER: persistent recurrence (r6 protocol) ===============
    float (*gx)[16][16] = (float (*)[16][16])ldsbuf;
    const int wid = bid;
    const int gw = wid * 8 + w;                   // 0..255
    const int hu0 = gw * 4;
    const int c = l & 15;
    const int n = (c >> 2) * H_ + hu0 + (c & 3);
    const int koff = (l >> 4) * 8;
    const int kgrp = (l >> 4) * 2;                // q-base = koff/4
    const int m = l & 15, u = l >> 4;
    const int hu = hu0 + u;
    const int m4 = m * 4;

    bf16x8 wf[32];
    {
      const u16* bp = WhT + (size_t)n * H_ + koff;
#pragma unroll
      for (int kk = 0; kk < 32; ++kk) wf[kk] = ldb8(bp + kk * 32);
    }

    float Cs = 0.0f;
    u64* HsU64 = (u64*)Hs;
    const u32* myflag = &ctl[(l & 31) * FLAG_STRIDE];

    for (int t = 0; t < T_; ++t) {
      const f32x4 g4 = *(const f32x4*)&Gx[((size_t)t * 4096 + n) * 16 + (size_t)(l >> 4) * 4];

      if (t > 0) {
        if (w == 0) {
          while (true) {
            u32 v = ld_agent(myflag);
            if (__all((int)(v >= (u32)t))) break;
            __builtin_amdgcn_s_sleep(1);
          }
          if (wid == 0 && l == 0) st_agent(&ctl[PROG_IDX], (u32)t);
        }
        __syncthreads();
      }

      // A-frags from line layout Hs[t][q][m]
      const u16* hrow = Hs + (size_t)t * 16384 + m4;
      f32x4 a0 = {}, a1 = {}, a2 = {}, a3 = {};
#pragma unroll
      for (int kk = 0; kk < 32; kk += 4) {
        a0 = __builtin_amdgcn_mfma_f32_16x16x32_bf16(mk2(hrow + (kgrp + (kk + 0) * 8) * 64), wf[kk + 0], a0, 0, 0, 0);
        a1 = __builtin_amdgcn_mfma_f32_16x16x32_bf16(mk2(hrow + (kgrp + (kk + 1) * 8) * 64), wf[kk + 1], a1, 0, 0, 0);
        a2 = __builtin_amdgcn_mfma_f32_16x16x32_bf16(mk2(hrow + (kgrp + (kk + 2) * 8) * 64), wf[kk + 2], a2, 0, 0, 0);
        a3 = __builtin_amdgcn_mfma_f32_16x16x32_bf16(mk2(hrow + (kgrp + (kk + 3) * 8) * 64), wf[kk + 3], a3, 0, 0, 0);
      }
      f32x4 acc = (a0 + a1) + (a2 + a3);

#pragma unroll
      for (int j = 0; j < 4; ++j)
        gx[w][(l >> 4) * 4 + j][c] = acc[j] + g4[j];

      float gi = gx[w][m][0 + u];
      float gf = gx[w][m][4 + u];
      float go = gx[w][m][8 + u];
      float gc = gx[w][m][12 + u];
      float I = fsig(gi);
      float F = fsig(gf);
      float O = fsig(go);
      float Ct = ftanh(gc);
      Cs = F * Cs + I * Ct;
      float Hn = O * ftanh(Cs);

      // pack u64 (units hu0..hu0+3 of batch m); 16 lanes = ONE 128B line
      u32 hb = (u32)f2bf(Hn);
      u32 h1 = __shfl_down(hb, 16);
      u32 h2 = __shfl_down(hb, 32);
      u32 h3 = __shfl_down(hb, 48);
      if (l < 16) {
        u64 pk = (u64)hb | ((u64)h1 << 16) | ((u64)h2 << 32) | ((u64)h3 << 48);
        __hip_atomic_store(&HsU64[(size_t)(t + 1) * 4096 + (size_t)gw * 16 + l], pk,
                           __ATOMIC_RELAXED, __HIP_MEMORY_SCOPE_AGENT);
      }
      if (t == T_ - 1) {
        outH[(size_t)m * H_ + hu] = Hn;
        outC[(size_t)m * H_ + hu] = Cs;
      }

      asm volatile("s_waitcnt vmcnt(0)" ::: "memory");
      __syncthreads();
      if (tid == 0) st_agent(&ctl[wid * FLAG_STRIDE], (u32)(t + 1));
    }

    // final: worker 0 publishes PROG=256 when all flags hit 256
    if (wid == 0 && w == 0) {
      while (true) {
        u32 v = ld_agent(myflag);
        if (__all((int)(v >= (u32)T_))) break;
        __builtin_amdgcn_s_sleep(1);
      }
      if (l == 0) st_agent(&ctl[PROG_IDX], (u32)T_);
    }
    return;
  }

  // =============== CONSUMER: Ys = Hs @ WqT + bq ===============
  u16* Bs = (u16*)ldsbuf;                        // [64][BSROW]
  const int cid = bid - NWORK;                   // 0..223
  const int nloc = (w & 3) * 16 + (l & 15);      // col within 64-strip
  const int mhalf = w >> 2;                      // 0..1 (rows 0-63 / 64-127 of mt tile)
  const int koff = (l >> 4) * 8;
  const int kgrp = (l >> 4) * 2;
  const int m4 = (l & 15) * 4;
  const size_t tv = (size_t)T_ * V_;

  for (int mt = 0; mt < 32; ++mt) {
    if (tid == 0) {
      const u32 need = (u32)(mt * 8 + 8);
      while (ld_agent(&ctl[PROG_IDX]) < need)
        __builtin_amdgcn_s_sleep(32);
    }
    __syncthreads();

    for (int s = cid; s < NSTRIP; s += NCONS) {
      const int n0 = s * 64;
      // stage B strip: wave w stages rows w*8 .. w*8+7 (2x 1KB per row)
#pragma unroll
      for (int r8 = 0; r8 < 8; ++r8) {
        int row = w * 8 + r8;
        const u16* src = WqT + (size_t)(n0 + row) * H_;
        u16* dst = Bs + row * BSROW;
        gll16(src + l * 8, dst);
        gll16(src + 512 + l * 8, dst + 512);
      }
      asm volatile("s_waitcnt vmcnt(0)" ::: "memory");
      __syncthreads();

      f32x4 acc[4] = {};
      const u16* hbase = Hs + (size_t)(mt * 8 + mhalf * 4 + 1) * 16384 + m4;
      const u16* bsrow = Bs + nloc * BSROW + koff;
#pragma unroll 4
      for (int kk = 0; kk < 32; ++kk) {
        bf16x8 bf = ldb8(bsrow + kk * 32);
        const int qo = (kgrp + kk * 8) * 64;
        acc[0] = __builtin_amdgcn_mfma_f32_16x16x32_bf16(mk2(hbase + 0 * 16384 + qo), bf, acc[0], 0, 0, 0);
        acc[1] = __builtin_amdgcn_mfma_f32_16x16x32_bf16(mk2(hbase + 1 * 16384 + qo), bf, acc[1], 0, 0, 0);
        acc[2] = __builtin_amdgcn_mfma_f32_16x16x32_bf16(mk2(hbase + 2 * 16384 + qo), bf, acc[2], 0, 0, 0);
        acc[3] = __builtin_amdgcn_mfma_f32_16x16x32_bf16(mk2(hbase + 3 * 16384 + qo), bf, acc[3], 0, 0, 0);
      }

      const int nn = n0 + nloc;
      const float bv = bqv[nn];
#pragma unroll
      for (int tm = 0; tm < 4; ++tm) {
        const int t_glob = mt * 8 + mhalf * 4 + tm;
#pragma unroll
        for (int j = 0; j < 4; ++j) {
          out[(size_t)((l >> 4) * 4 + j) * tv + (size_t)t_glob * V_ + nn] = acc[tm][j] + bv;
        }
      }
      __syncthreads();   // protect Bs before next strip's staging
    }
  }
}

// ---------------- host launcher ----------------

extern "C" void kernel_launch(void* const* d_in, const int* in_sizes, int n_in,
                              void* d_out, int out_size, void* d_ws, size_t ws_size,
                              hipStream_t stream) {
  const int*   ids = (const int*)d_in[0];
  const float* emb = (const float*)d_in[1];
  const float* Wxi = (const float*)d_in[2];
  const float* Whi = (const float*)d_in[3];
  const float* bi  = (const float*)d_in[4];
  const float* Wxf = (const float*)d_in[5];
  const float* Whf = (const float*)d_in[6];
  const float* bfv = (const float*)d_in[7];
  const float* Wxo = (const float*)d_in[8];
  const float* Who = (const float*)d_in[9];
  const float* bo  = (const float*)d_in[10];
  const float* Wxc = (const float*)d_in[11];
  const float* Whc = (const float*)d_in[12];
  const float* bc  = (const float*)d_in[13];
  const float* Whq = (const float*)d_in[14];
  const float* bq  = (const float*)d_in[15];
  float* out = (float*)d_out;

  char* ws = (char*)d_ws;
  u16* WxT = (u16*)ws;      ws += (size_t)4096 * H_ * 2;
  u16* WhT = (u16*)ws;      ws += (size_t)4096 * H_ * 2;
  u16* WqT = (u16*)ws;      ws += (size_t)V_ * H_ * 2;
  u16* Emb = (u16*)ws;      ws += (size_t)T_ * B_ * H_ * 2;
  float* Gx = (float*)ws;   ws += (size_t)T_ * 4096 * B_ * 4;
  u16* Hs  = (u16*)ws;      ws += (size_t)(T_ + 1) * B_ * H_ * 2;
  float* bfu = (float*)ws;  ws += (size_t)4096 * 4;
  u32* ctl = (u32*)ws;      ws += (size_t)CTL_WORDS * 4;

  // P0: prep
  k_init<<<64, 256, 0, stream>>>((u32*)Hs, ctl, bfu, bi, bfv, bo, bc);
  k_embed<<<4096, 256, 0, stream>>>(ids, emb, Emb);
  k_fuse8<<<dim3(16, 16, 8), 256, 0, stream>>>(Wxi, Wxf, Wxo, Wxc, Whi, Whf, Who, Whc, WxT, WhT);
  k_transq<<<dim3(500, 16), 256, 0, stream>>>(Whq, WqT);

  // P1: Gx = emb @ Wx + b
  gemm_gx<<<dim3(32, 32), 256, 0, stream>>>(Emb, WxT, bfu, Gx, 4096, H_);

  // P2+P3 fused: recurrence (blocks 0-31) + Ys consumers (blocks 32-255)
  float* outH = out + (size_t)B_ * T_ * V_;
  float* outC = outH + (size_t)B_ * H_;
  fused<<<NWORK + NCONS, 512, 0, stream>>>(WhT, WqT, Gx, Hs, ctl, bq, out, outH, outC);
}